// Round 14
// baseline (49.072 us; speedup 1.0000x reference)
//
#include <hip/hip_runtime.h>

#define BATCH 32
#define LATENT 128
#define NODE_DIM 8
#define MAX_NODES 512
#define H_NODE 128
#define H_EDGE 64

typedef _Float16 h2 __attribute__((ext_vector_type(2)));

static __device__ __forceinline__ h2 u32_to_h2(unsigned int x) {
    union { unsigned int u; h2 h; } c; c.u = x; return c.h;
}
static __device__ __forceinline__ unsigned int h2_to_u32(h2 x) {
    union { unsigned int u; h2 h; } c; c.h = x; return c.u;
}

#if __has_builtin(__builtin_amdgcn_fdot2)
#define FDOT2(a, b, c) __builtin_amdgcn_fdot2((a), (b), (c), false)
#else
#define FDOT2(a, b, c) ((c) + (float)(a).x * (float)(b).x + (float)(a).y * (float)(b).y)
#endif

// ws layout: UPKH u32[32][32][512] (2MB) | VH u32[32][512][32] (2MB)
//            | E2H u32[32] | Hws f32[32][128]
#define UPKH_DWORDS (BATCH * 32 * MAX_NODES)
#define VH_DWORDS   (BATCH * MAX_NODES * 32)

// ---------------------------------------------------------------------------
// Kernel 0 (unchanged): h = relu(z@W1+b1) per batch -> ws. 32 blocks.
// ---------------------------------------------------------------------------
__global__ __launch_bounds__(128) void h_gen(
    const float* __restrict__ z, const float* __restrict__ W1,
    const float* __restrict__ b1, float* __restrict__ Hws)
{
    const int b = blockIdx.x, tid = threadIdx.x;
    __shared__ float sz[LATENT];
    sz[tid] = z[b * LATENT + tid];
    __syncthreads();
    float acc = b1[tid];
#pragma unroll 8
    for (int k = 0; k < LATENT; ++k)
        acc += sz[k] * W1[k * H_NODE + tid];
    Hws[b * H_NODE + tid] = fmaxf(acc, 0.0f);
}

// ---------------------------------------------------------------------------
// Kernel 1 (unchanged): nodes (f32, d_out) + U/V packed f16 + E2 packing.
// ---------------------------------------------------------------------------
__global__ __launch_bounds__(256) void gen_nodes_uv(
    const float* __restrict__ Hws, const float* __restrict__ W2,
    const float* __restrict__ b2,  const float* __restrict__ E1,
    const float* __restrict__ eb1, const float* __restrict__ E2,
    float* __restrict__ nodes_out, unsigned int* __restrict__ UPKH,
    unsigned int* __restrict__ VH, unsigned int* __restrict__ E2H)
{
    const int b      = blockIdx.x;
    const int mslice = blockIdx.y;     // 0..15, 256 cols each
    const int tid    = threadIdx.x;    // 0..255
    const int i0     = mslice * 32;    // first node owned by this block

    __shared__ float sh[H_NODE];
    __shared__ float sE1[2 * NODE_DIM][H_EDGE];
    __shared__ float sEb1[H_EDGE];
    __shared__ float sN[32][NODE_DIM];

    if (tid < H_NODE) sh[tid] = Hws[b * H_NODE + tid];
    for (int idx = tid; idx < 2 * NODE_DIM * H_EDGE; idx += 256)
        (&sE1[0][0])[idx] = E1[idx];
    if (tid < H_EDGE) sEb1[tid] = eb1[tid];

    if (b == 0 && mslice == 0 && tid < 32) {
        h2 w = { (_Float16)E2[2 * tid], (_Float16)E2[2 * tid + 1] };
        E2H[tid] = h2_to_u32(w);
    }
    __syncthreads();

    const int m = mslice * 256 + tid;
    float acc = b2[m];
#pragma unroll 8
    for (int k = 0; k < H_NODE; ++k)
        acc += sh[k] * W2[(size_t)k * (MAX_NODES * NODE_DIM) + m];
    nodes_out[(size_t)b * (MAX_NODES * NODE_DIM) + m] = acc;
    sN[tid >> 3][tid & 7] = acc;
    __syncthreads();

    {   // U' -> f16x2, layout [b][c2][i]
        const int il = tid & 31;
        const int cg = tid >> 5;
#pragma unroll
        for (int rep = 0; rep < 4; ++rep) {
            const int c2 = rep * 8 + cg;
            const int c  = 2 * c2;
            float ua = sEb1[c], ub = sEb1[c + 1];
#pragma unroll
            for (int d = 0; d < NODE_DIM; ++d) {
                const float nd = sN[il][d];
                ua += nd * sE1[d][c];
                ub += nd * sE1[d][c + 1];
            }
            h2 uu = { (_Float16)ua, (_Float16)ub };
            UPKH[((size_t)b * 32 + c2) * MAX_NODES + i0 + il] = h2_to_u32(uu);
        }
    }
    {   // V' -> f16x2, layout [b][j][c2] (128B rows)
        const int jl = tid >> 3;
        const int cq = tid & 7;
#pragma unroll
        for (int rep = 0; rep < 4; ++rep) {
            const int c2 = rep * 8 + cq;
            const int c  = 2 * c2;
            float va = 0.f, vb = 0.f;
#pragma unroll
            for (int d = 0; d < NODE_DIM; ++d) {
                const float nd = sN[jl][d];
                va += nd * sE1[NODE_DIM + d][c];
                vb += nd * sE1[NODE_DIM + d][c + 1];
            }
            h2 vv = { (_Float16)va, (_Float16)vb };
            VH[((size_t)(b * MAX_NODES + i0 + jl) << 5) + c2] = h2_to_u32(vv);
        }
    }
}

// ---------------------------------------------------------------------------
// k=1 channel sweep (64-ch f16 dot for one i).
// ---------------------------------------------------------------------------
static __device__ __forceinline__ float edge_dot(
    const uint4* vrow, const unsigned int (&uA)[32], const unsigned int (&wb)[32])
{
    const h2 zh = { (_Float16)0.f, (_Float16)0.f };
    float a0 = 0.f, a1 = 0.f;
#pragma unroll
    for (int q = 0; q < 8; ++q) {
        union { uint4 u4; unsigned int u[4]; } vv;
        vv.u4 = vrow[q];
#pragma unroll
        for (int k = 0; k < 4; ++k) {
            const int c2 = 4 * q + k;
            h2 s = u32_to_h2(uA[c2]) + u32_to_h2(vv.u[k]);
            s = __builtin_elementwise_max(s, zh);
            if (k & 1) a1 = FDOT2(s, u32_to_h2(wb[c2]), a1);
            else       a0 = FDOT2(s, u32_to_h2(wb[c2]), a0);
        }
    }
    return a0 + a1;
}

// ---------------------------------------------------------------------------
// Kernel 2: edge probabilities + adjacency.
// KEY CHANGE (R14): k=2 i-rows per lane on the bulk tiles. Per broadcast
// ds_read_b128 the wave now executes 2x the VALU -> LDS:VALU demand 1:1
// (was 2:1 -> the measured VALUBusy~50% plateau of R4-R13).
// 48 tiles/batch: x<24: full 128i x 32j (k=2); x in 24..31: cross 64i x 32j
// full (k=1); x>=32: partial 64i x 32j (R10's predicated diagonal, k=1).
// Exact-once pair coverage verified by construction.
// ---------------------------------------------------------------------------
__global__ __launch_bounds__(256, 4) void edge_gen(
    const unsigned int* __restrict__ UPKH, const unsigned int* __restrict__ VH,
    const unsigned int* __restrict__ E2H, const float* __restrict__ eb2,
    float* __restrict__ adj)
{
    const int b = blockIdx.y;
    const int x = blockIdx.x;                // 0..47
    const int tid  = threadIdx.x;
    const int lane = tid & 63;
    const int wv   = tid >> 6;               // 0..3

    __shared__ unsigned int sV[32 * 32];     // 32 V rows (4 KB)
    __shared__ float P[32][129];             // mirror staging (16.5 KB)

    int i0, j0, type;                        // 0=full128(k2) 1=full64 2=part64
    if (x < 24) {
        int bb, jt;
        if (x < 12)      { bb = 0; jt = 4 + x; }
        else if (x < 20) { bb = 1; jt = 8 + (x - 12); }
        else             { bb = 2; jt = 12 + (x - 20); }
        i0 = bb * 128; j0 = jt * 32; type = 0;
    } else if (x < 32) {
        const int idx = x - 24, a = idx >> 1, hf = idx & 1;
        i0 = a * 128; j0 = a * 128 + 64 + hf * 32; type = 1;
    } else {
        const int idx = x - 32, bi = idx >> 1;
        i0 = bi * 64; j0 = bi * 64 + (idx & 1) * 32; type = 2;
    }

    // stage V tile (32 rows, 4 KB contiguous)
    {
        const uint4* src = (const uint4*)(VH + ((size_t)(b * MAX_NODES + j0) << 5));
        ((uint4*)sV)[tid] = src[tid];
    }

    unsigned int wb[32];
#pragma unroll
    for (int c2 = 0; c2 < 32; ++c2) wb[c2] = E2H[c2];

    const float bias = eb2[0];
    float* adjb = adj + (size_t)b * MAX_NODES * MAX_NODES;
    const h2 zh = { (_Float16)0.f, (_Float16)0.f };

    if (type == 0) {
        // ---- full 128i x 32j, two i's per lane ----
        const int iA = i0 + lane, iB = iA + 64;
        unsigned int uA[32], uB[32];
#pragma unroll
        for (int c2 = 0; c2 < 32; ++c2) {
            const unsigned int* base = &UPKH[((size_t)b * 32 + c2) * MAX_NODES];
            uA[c2] = base[iA];
            uB[c2] = base[iB];
        }
        __syncthreads();

#pragma unroll 1
        for (int jj = 0; jj < 8; ++jj) {
            const int jl = wv * 8 + jj;
            const int j  = j0 + jl;
            const uint4* vrow = (const uint4*)&sV[jl * 32];

            float aA0 = 0.f, aA1 = 0.f, aB0 = 0.f, aB1 = 0.f;
#pragma unroll
            for (int q = 0; q < 8; ++q) {
                union { uint4 u4; unsigned int u[4]; } vv;
                vv.u4 = vrow[q];
#pragma unroll
                for (int k = 0; k < 4; ++k) {
                    const int c2 = 4 * q + k;
                    const h2 v = u32_to_h2(vv.u[k]);
                    const h2 w = u32_to_h2(wb[c2]);
                    h2 sA = u32_to_h2(uA[c2]) + v;
                    h2 sB = u32_to_h2(uB[c2]) + v;
                    sA = __builtin_elementwise_max(sA, zh);
                    sB = __builtin_elementwise_max(sB, zh);
                    if (k & 1) { aA1 = FDOT2(sA, w, aA1); aB1 = FDOT2(sB, w, aB1); }
                    else       { aA0 = FDOT2(sA, w, aA0); aB0 = FDOT2(sB, w, aB0); }
                }
            }
            const float xA = aA0 + aA1 + bias;
            const float xB = aB0 + aB1 + bias;
            const float pA = __builtin_amdgcn_rcpf(1.0f + __expf(-xA));
            const float pB = __builtin_amdgcn_rcpf(1.0f + __expf(-xB));

            adjb[(size_t)j * MAX_NODES + iA] = pA;   // coalesced 256B halves
            adjb[(size_t)j * MAX_NODES + iB] = pB;
            P[jl][lane]      = pA;                   // stage for mirror
            P[jl][64 + lane] = pB;
        }
        __syncthreads();

        // mirror: adj[i0+r][j0..j0+31]; r = tid&127, half h -> 16 cols
        const int r = tid & 127;
        const int h = tid >> 7;
        const size_t rowbase = (size_t)(i0 + r) * MAX_NODES + j0 + h * 16;
#pragma unroll
        for (int g = 0; g < 4; ++g) {
            const int c0 = h * 16 + 4 * g;
            float4 o;
            o.x = P[c0 + 0][r]; o.y = P[c0 + 1][r];
            o.z = P[c0 + 2][r]; o.w = P[c0 + 3][r];
            *(float4*)&adjb[rowbase + 4 * g] = o;
        }
    } else {
        // ---- 64i x 32j, k=1 (cross-full or diagonal-partial) ----
        const int i = i0 + lane;
        unsigned int uA[32];
#pragma unroll
        for (int c2 = 0; c2 < 32; ++c2)
            uA[c2] = UPKH[((size_t)b * 32 + c2) * MAX_NODES + i];
        __syncthreads();

        const bool partial = (type == 2);    // block-uniform

#pragma unroll 1
        for (int jj = 0; jj < 8; ++jj) {
            const int jl = wv * 8 + jj;
            const int j  = j0 + jl;
            const float xs = edge_dot((const uint4*)&sV[jl * 32], uA, wb) + bias;
            const float p  = __builtin_amdgcn_rcpf(1.0f + __expf(-xs));

            if (!partial) {
                adjb[(size_t)j * MAX_NODES + i] = p;
                P[jl][lane] = p;
            } else {
                if (i < j)       { adjb[(size_t)j * MAX_NODES + i] = p;
                                   adjb[(size_t)i * MAX_NODES + j] = p; }
                else if (i == j)   adjb[(size_t)j * MAX_NODES + i] = 0.0f;
            }
        }

        if (!partial) {
            __syncthreads();
            const int r = tid & 63;
            const int q = tid >> 6;
            const size_t rowbase = (size_t)(i0 + r) * MAX_NODES + j0 + q * 8;
            float4 o0, o1;
            o0.x = P[q * 8 + 0][r]; o0.y = P[q * 8 + 1][r];
            o0.z = P[q * 8 + 2][r]; o0.w = P[q * 8 + 3][r];
            o1.x = P[q * 8 + 4][r]; o1.y = P[q * 8 + 5][r];
            o1.z = P[q * 8 + 6][r]; o1.w = P[q * 8 + 7][r];
            *(float4*)&adjb[rowbase]     = o0;
            *(float4*)&adjb[rowbase + 4] = o1;
        }
    }
}

// ---------------------------------------------------------------------------
extern "C" void kernel_launch(void* const* d_in, const int* in_sizes, int n_in,
                              void* d_out, int out_size, void* d_ws, size_t ws_size,
                              hipStream_t stream)
{
    const float* z   = (const float*)d_in[0];
    const float* W1  = (const float*)d_in[1];
    const float* b1  = (const float*)d_in[2];
    const float* W2  = (const float*)d_in[3];
    const float* b2  = (const float*)d_in[4];
    const float* E1  = (const float*)d_in[5];
    const float* eb1 = (const float*)d_in[6];
    const float* E2  = (const float*)d_in[7];
    const float* eb2 = (const float*)d_in[8];

    float* nodes_out = (float*)d_out;                                   // [32,512,8]
    float* adj       = (float*)d_out + BATCH * MAX_NODES * NODE_DIM;    // [32,512,512]

    unsigned int* UPKH = (unsigned int*)d_ws;       // 2 MB
    unsigned int* VHp  = UPKH + UPKH_DWORDS;        // 2 MB
    unsigned int* E2H  = VHp + VH_DWORDS;           // 128 B
    float*        Hws  = (float*)(E2H + 32);        // 16 KB

    h_gen<<<BATCH, 128, 0, stream>>>(z, W1, b1, Hws);

    dim3 g1(BATCH, 16);
    gen_nodes_uv<<<g1, 256, 0, stream>>>(Hws, W2, b2, E1, eb1, E2,
                                         nodes_out, UPKH, VHp, E2H);

    dim3 g2(48, BATCH);
    edge_gen<<<g2, 256, 0, stream>>>(UPKH, VHp, E2H, eb2, adj);
}